// Round 5
// baseline (613.380 us; speedup 1.0000x reference)
//
#include <hip/hip_runtime.h>
#include <hip/hip_bf16.h>

typedef unsigned long long ull;

// ---------------- problem constants ----------------
constexpr int BATCH = 8;
constexpr int NA    = 261888;
constexpr int KSEL  = 6000;          // PRE_NMS_LIMIT
constexpr int PROP  = 1000;          // PROPOSAL_COUNT
constexpr int CAP   = 8192;          // candidate capacity (pow2 for bitonic)
constexpr int NBINS = 8192;          // histogram bins
constexpr int HB    = 16;            // private histogram blocks per batch
constexpr int NB    = (KSEL + 63) / 64;   // 94 mask words per row
constexpr int NWP   = 96;            // padded words per row (96*8 = 768B rows)

// workspace layout (bytes). keys and hist BOTH alias the mask head:
//   hist lives hist_kernel -> thresh_kernel
//   keys lives compact_kernel -> sortbox_kernel
//   mask lives mask_kernel -> scan_kernel       (all disjoint in time)
constexpr size_t OFF_CNT   = 0;                       // 8*16*4 = 512
constexpr size_t OFF_TSEL  = 512;                     // 32
constexpr size_t OFF_BOXES = 544;                     // 8*6000*16 = 768000
constexpr size_t OFF_MASK  = 769024;                  // 8*6000*96*8 = 36864000
constexpr size_t OFF_KEYS  = OFF_MASK;                // 524288 (aliased)
constexpr size_t OFF_HIST  = OFF_MASK;                // 4MB (aliased)
// total = 769024 + 36864000 = 37,633,024 B  (<= proven 37,650,496)

__device__ __forceinline__ int score_bin(float s) {
  int b = (int)(s * (float)NBINS);
  if (b < 0) b = 0;
  if (b > NBINS - 1) b = NBINS - 1;
  return b;
}

// ---------------- 1. histogram (private per-block copies, no global atomics) ----------------
__global__ __launch_bounds__(256) void hist_kernel(const float2* __restrict__ probs,
                                                   unsigned int* __restrict__ hist) {
  __shared__ unsigned int lh[NBINS];
  for (int i = threadIdx.x; i < NBINS; i += 256) lh[i] = 0u;
  __syncthreads();
  int b = blockIdx.y;
  const float2* p = probs + (size_t)b * NA;
  for (int a = blockIdx.x * 256 + threadIdx.x; a < NA; a += HB * 256) {
    atomicAdd(&lh[score_bin(p[a].y)], 1u);
  }
  __syncthreads();
  unsigned int* gh = hist + ((size_t)b * HB + blockIdx.x) * NBINS;
  for (int i = threadIdx.x; i < NBINS; i += 256) gh[i] = lh[i];
}

// ---------------- 2. threshold bin select ----------------
__global__ __launch_bounds__(256) void thresh_kernel(const unsigned int* __restrict__ hist,
                                                     int* __restrict__ tsel) {
  constexpr int GR = NBINS / 256; // 32 bins per thread
  __shared__ unsigned int ch[NBINS];
  __shared__ unsigned int gsum[256];
  int b = blockIdx.x;
  const unsigned int* h = hist + (size_t)b * HB * NBINS;
  for (int bin = threadIdx.x; bin < NBINS; bin += 256) {
    unsigned int s = 0;
    for (int k = 0; k < HB; ++k) s += h[(size_t)k * NBINS + bin];
    ch[bin] = s;
  }
  __syncthreads();
  unsigned int s = 0;
  int g0 = threadIdx.x * GR;
  for (int i = 0; i < GR; ++i) s += ch[g0 + i];
  gsum[threadIdx.x] = s;
  __syncthreads();
  if (threadIdx.x == 0) {
    unsigned int acc = 0;
    int g = 255;
    for (; g > 0; --g) {
      if (acc + gsum[g] >= (unsigned)KSEL) break;
      acc += gsum[g];
    }
    int t = g * GR;
    for (int bin = g * GR + GR - 1; bin >= g * GR; --bin) {
      acc += ch[bin];
      if (acc >= (unsigned)KSEL) { t = bin; break; }
    }
    tsel[b] = t;
  }
}

// ---------------- 3. compact candidates (block-aggregated, 1 global atomic/block) ----------------
__global__ __launch_bounds__(256) void compact_kernel(const float2* __restrict__ probs,
                                                      const int* __restrict__ tsel,
                                                      int* __restrict__ cnt,
                                                      ull* __restrict__ keys) {
  __shared__ int lcnt, lbase;
  __shared__ ull lbuf[2048]; // block covers <=2048 anchors
  int b = blockIdx.y;
  int t = tsel[b];
  if (threadIdx.x == 0) lcnt = 0;
  __syncthreads();
  const float2* p = probs + (size_t)b * NA;
  for (int a = blockIdx.x * blockDim.x + threadIdx.x; a < NA; a += gridDim.x * blockDim.x) {
    float s = p[a].y;
    if (score_bin(s) >= t) {
      int pos = atomicAdd(&lcnt, 1);
      unsigned int ib = ~__float_as_uint(s); // score>=0: ~bits ascending == score descending
      lbuf[pos] = ((ull)ib << 32) | (unsigned int)a;
    }
  }
  __syncthreads();
  if (threadIdx.x == 0) lbase = atomicAdd(&cnt[b * 16], lcnt);
  __syncthreads();
  int n = lcnt, base = lbase;
  ull* kb = keys + (size_t)b * CAP;
  for (int i = threadIdx.x; i < n; i += 256) {
    int pos = base + i;
    if (pos < CAP) kb[pos] = lbuf[i];
  }
}

// ---------------- 4. bitonic sort + box decode ----------------
__global__ __launch_bounds__(1024) void sortbox_kernel(const float4* __restrict__ anchors4,
                                                       const float4* __restrict__ bbox4,
                                                       const int* __restrict__ cnt,
                                                       const ull* __restrict__ keys,
                                                       float4* __restrict__ boxes4) {
#pragma clang fp contract(off)
  __shared__ ull sh[CAP];
  int b = blockIdx.x;
  int n = cnt[b * 16];
  if (n > CAP) n = CAP;
  const ull* kb = keys + (size_t)b * CAP;
  for (int i = threadIdx.x; i < CAP; i += 1024) sh[i] = (i < n) ? kb[i] : ~0ull;
  __syncthreads();
  for (int k = 2; k <= CAP; k <<= 1) {
    for (int j = k >> 1; j > 0; j >>= 1) {
      for (int i = threadIdx.x; i < CAP; i += 1024) {
        int ixj = i ^ j;
        if (ixj > i) {
          ull a = sh[i], c = sh[ixj];
          bool up = ((i & k) == 0);
          if ((a > c) == up) { sh[i] = c; sh[ixj] = a; }
        }
      }
      __syncthreads();
    }
  }
  for (int r = threadIdx.x; r < KSEL; r += 1024) {
    int a = (int)(unsigned int)sh[r];
    float4 anc = anchors4[(size_t)b * NA + a];
    float4 d   = bbox4[(size_t)b * NA + a];
    float h = anc.z - anc.x;
    float w = anc.w - anc.y;
    float dy = d.x * 0.1f, dx = d.y * 0.1f, dh = d.z * 0.2f, dw = d.w * 0.2f;
    float cy = (anc.x + (0.5f * h)) + (dy * h);
    float cx = (anc.y + (0.5f * w)) + (dx * w);
    float h2 = h * expf(dh);
    float w2 = w * expf(dw);
    float y1 = cy - 0.5f * h2;
    float x1 = cx - 0.5f * w2;
    float y2 = y1 + h2;
    float x2 = x1 + w2;
    y1 = fminf(fmaxf(y1, 0.f), 1.f);
    x1 = fminf(fmaxf(x1, 0.f), 1.f);
    y2 = fminf(fmaxf(y2, 0.f), 1.f);
    x2 = fminf(fmaxf(x2, 0.f), 1.f);
    boxes4[(size_t)b * KSEL + r] = make_float4(y1, x1, y2, x2);
  }
}

// ---------------- 5. suppression mask, ROW-major [b][row][96] words ----------------
// block = 256 threads = 4 waves; block owns 64 rows; wave wv computes col-blocks wv, wv+4, ...
// words accumulate in LDS wtile[64][97], flushed fully coalesced at the end.
__global__ __launch_bounds__(256) void mask_kernel(const float4* __restrict__ boxes4,
                                                   ull* __restrict__ mask) {
#pragma clang fp contract(off)
  __shared__ ull wtile[64][97];     // 49.7 KB, 97 pad -> 2-way banks on word writes
  __shared__ float4 colbox[4][64];  // per-wave col stage
  int rb = blockIdx.x, b = blockIdx.y;
  int tid = threadIdx.x;
  int wv = tid >> 6, l = tid & 63;
  for (int idx = tid; idx < 64 * 97; idx += 256) (&wtile[0][0])[idx] = 0ull;
  int row = rb * 64 + l;
  float4 r = (row < KSEL) ? boxes4[(size_t)b * KSEL + row] : make_float4(0.f, 0.f, 0.f, 0.f);
  float ra = (r.z - r.x) * (r.w - r.y);
  __syncthreads();
  for (int cb = wv; cb < NB; cb += 4) {
    if (cb < rb) continue;           // wholly-lower tiles stay zero
    int c = cb * 64 + l;
    colbox[wv][l] = (c < KSEL) ? boxes4[(size_t)b * KSEL + c] : make_float4(0.f, 0.f, 0.f, 0.f);
    asm volatile("s_waitcnt lgkmcnt(0)" ::: "memory");
    ull bits = 0ull;
    int c0 = cb * 64;
    for (int u = 0; u < 64; ++u) {
      int cc = c0 + u;
      if (cc > row) {
        float4 cb4 = colbox[wv][u];
        float ca = (cb4.z - cb4.x) * (cb4.w - cb4.y);
        float ih = fmaxf(fminf(r.z, cb4.z) - fmaxf(r.x, cb4.x), 0.f);
        float iw = fmaxf(fminf(r.w, cb4.w) - fmaxf(r.y, cb4.y), 0.f);
        float inter = ih * iw;
        float uni = (ra + ca) - inter;
        float iou = (uni > 0.f) ? (inter / uni) : 0.f;
        if (iou > 0.7f) bits |= (1ull << u);
      }
    }
    wtile[l][cb] = bits;
  }
  __syncthreads();
  // coalesced flush: global row-major stride 96 makes the tile contiguous
  ull* gm = mask + ((size_t)b * KSEL + (size_t)rb * 64) * NWP;
  int nrows = min(64, KSEL - rb * 64);
  for (int idx = tid; idx < nrows * NWP; idx += 256) {
    int rr = idx / NWP, w = idx - rr * NWP;
    gm[idx] = wtile[rr][w];
  }
}

// ---------------- 6. single-wave greedy scan, all state in registers ----------------
// lane l holds words 2l,2l+1 of: the suppressed-bitmap (Sx,Sy) and each prefetched row.
// Decision chain: v_readlane from owner lane -> uniform bit test -> uniform branch.
__global__ __launch_bounds__(64, 1) void scan_kernel(const float4* __restrict__ boxes4,
                                                     const ull* __restrict__ mask,
                                                     float4* __restrict__ out4) {
  __shared__ int skeep[PROP];
  int b = blockIdx.x;
  int lane = threadIdx.x;
  const ull* mb = mask + (size_t)b * KSEL * NWP;
  int col = (2 * lane < NB) ? 2 * lane : NB;   // lanes >=47 read pad words 94,95 (zeros)

  ulonglong2 r[32];                 // 32-row prefetch ring, statically indexed
#pragma unroll
  for (int k = 0; k < 32; ++k)
    r[k] = *(const ulonglong2*)(mb + (size_t)k * NWP + col);

  ull Sx = 0ull, Sy = 0ull;         // suppressed words 2*lane, 2*lane+1
  int kept = 0;
  bool done = false;

  for (int i0 = 0; i0 < KSEL && !done; i0 += 64) {
    int w  = i0 >> 6;               // uniform: same word for all 64 rows of this block
    int ol = w >> 1;                // owner lane
    auto run = [&](bool useY) {
#pragma unroll
      for (int u = 0; u < 64; ++u) {
        int i = i0 + u;
        if (i >= KSEL) { done = true; break; }
        ull Ssel = useY ? Sy : Sx;
        unsigned int piece = (u < 32) ? (unsigned int)Ssel : (unsigned int)(Ssel >> 32);
        unsigned int v = (unsigned int)__builtin_amdgcn_readlane((int)piece, ol);
        if (!((v >> (u & 31)) & 1u)) {
          if (lane == 0) skeep[kept] = i;
          ++kept;
          if (kept >= PROP) { done = true; break; }
          Sx |= r[u & 31].x;
          Sy |= r[u & 31].y;
        }
        if (i + 32 < KSEL)
          r[u & 31] = *(const ulonglong2*)(mb + (size_t)(i + 32) * NWP + col);
      }
    };
    if ((w & 1) == 0) run(false); else run(true);
  }

  __syncthreads();
  int fin = kept;
  for (int rr = lane; rr < PROP; rr += 64) {
    float4 v = make_float4(0.f, 0.f, 0.f, 0.f);
    if (rr < fin) v = boxes4[(size_t)b * KSEL + skeep[rr]];
    out4[(size_t)b * PROP + rr] = v;
  }
}

// ---------------- launch ----------------
extern "C" void kernel_launch(void* const* d_in, const int* in_sizes, int n_in,
                              void* d_out, int out_size, void* d_ws, size_t ws_size,
                              hipStream_t stream) {
  const float2* probs   = (const float2*)d_in[0];
  const float4* bbox4   = (const float4*)d_in[1];
  const float4* anchors4= (const float4*)d_in[2];
  float4* out4 = (float4*)d_out;
  char* ws = (char*)d_ws;

  int* cnt      = (int*)(ws + OFF_CNT);
  int* tsel     = (int*)(ws + OFF_TSEL);
  float4* boxes4= (float4*)(ws + OFF_BOXES);
  ull* maskw    = (ull*)(ws + OFF_MASK);
  ull* keys     = (ull*)(ws + OFF_KEYS);   // aliases mask head
  unsigned int* hist = (unsigned int*)(ws + OFF_HIST); // aliases mask head

  hipMemsetAsync(ws + OFF_CNT, 0, 544, stream);

  hipLaunchKernelGGL(hist_kernel,    dim3(HB, BATCH),  dim3(256),  0, stream, probs, hist);
  hipLaunchKernelGGL(thresh_kernel,  dim3(BATCH),      dim3(256),  0, stream, hist, tsel);
  hipLaunchKernelGGL(compact_kernel, dim3(128, BATCH), dim3(256),  0, stream, probs, tsel, cnt, keys);
  hipLaunchKernelGGL(sortbox_kernel, dim3(BATCH),      dim3(1024), 0, stream, anchors4, bbox4, cnt, keys, boxes4);
  hipLaunchKernelGGL(mask_kernel,    dim3(NB, BATCH),  dim3(256),  0, stream, boxes4, maskw);
  hipLaunchKernelGGL(scan_kernel,    dim3(BATCH),      dim3(64),   0, stream, boxes4, maskw, out4);
}

// Round 6
// 484.714 us; speedup vs baseline: 1.2654x; 1.2654x over previous
//
#include <hip/hip_runtime.h>
#include <hip/hip_bf16.h>

typedef unsigned long long ull;

// ---------------- problem constants ----------------
constexpr int BATCH = 8;
constexpr int NA    = 261888;
constexpr int KSEL  = 6000;          // PRE_NMS_LIMIT
constexpr int PROP  = 1000;          // PROPOSAL_COUNT
constexpr int CAP   = 8192;          // candidate capacity (pow2 for bitonic)
constexpr int NBINS = 8192;          // histogram bins
constexpr int HB    = 16;            // private histogram blocks per batch
constexpr int NB    = (KSEL + 63) / 64;   // 94 mask words per row
constexpr int NWP   = 96;            // padded words per row (96*8 = 768B rows)

// workspace layout (bytes). keys and hist BOTH alias the mask head (disjoint liveness).
constexpr size_t OFF_CNT   = 0;                       // 8*16*4 = 512
constexpr size_t OFF_TSEL  = 512;                     // 32
constexpr size_t OFF_BOXES = 544;                     // 8*6000*16 = 768000
constexpr size_t OFF_MASK  = 769024;                  // 8*6000*96*8 = 36864000
constexpr size_t OFF_KEYS  = OFF_MASK;                // 524288 (aliased)
constexpr size_t OFF_HIST  = OFF_MASK;                // 4MB (aliased)
// total = 37,633,024 B

__device__ __forceinline__ int score_bin(float s) {
  int b = (int)(s * (float)NBINS);
  if (b < 0) b = 0;
  if (b > NBINS - 1) b = NBINS - 1;
  return b;
}

// ---------------- 1. histogram (private per-block copies, no global atomics) ----------------
__global__ __launch_bounds__(256) void hist_kernel(const float2* __restrict__ probs,
                                                   unsigned int* __restrict__ hist) {
  __shared__ unsigned int lh[NBINS];
  for (int i = threadIdx.x; i < NBINS; i += 256) lh[i] = 0u;
  __syncthreads();
  int b = blockIdx.y;
  const float2* p = probs + (size_t)b * NA;
  for (int a = blockIdx.x * 256 + threadIdx.x; a < NA; a += HB * 256) {
    atomicAdd(&lh[score_bin(p[a].y)], 1u);
  }
  __syncthreads();
  unsigned int* gh = hist + ((size_t)b * HB + blockIdx.x) * NBINS;
  for (int i = threadIdx.x; i < NBINS; i += 256) gh[i] = lh[i];
}

// ---------------- 2. threshold bin select ----------------
__global__ __launch_bounds__(256) void thresh_kernel(const unsigned int* __restrict__ hist,
                                                     int* __restrict__ tsel) {
  constexpr int GR = NBINS / 256; // 32 bins per thread
  __shared__ unsigned int ch[NBINS];
  __shared__ unsigned int gsum[256];
  int b = blockIdx.x;
  const unsigned int* h = hist + (size_t)b * HB * NBINS;
  for (int bin = threadIdx.x; bin < NBINS; bin += 256) {
    unsigned int s = 0;
    for (int k = 0; k < HB; ++k) s += h[(size_t)k * NBINS + bin];
    ch[bin] = s;
  }
  __syncthreads();
  unsigned int s = 0;
  int g0 = threadIdx.x * GR;
  for (int i = 0; i < GR; ++i) s += ch[g0 + i];
  gsum[threadIdx.x] = s;
  __syncthreads();
  if (threadIdx.x == 0) {
    unsigned int acc = 0;
    int g = 255;
    for (; g > 0; --g) {
      if (acc + gsum[g] >= (unsigned)KSEL) break;
      acc += gsum[g];
    }
    int t = g * GR;
    for (int bin = g * GR + GR - 1; bin >= g * GR; --bin) {
      acc += ch[bin];
      if (acc >= (unsigned)KSEL) { t = bin; break; }
    }
    tsel[b] = t;
  }
}

// ---------------- 3. compact candidates (block-aggregated, 1 global atomic/block) ----------------
__global__ __launch_bounds__(256) void compact_kernel(const float2* __restrict__ probs,
                                                      const int* __restrict__ tsel,
                                                      int* __restrict__ cnt,
                                                      ull* __restrict__ keys) {
  __shared__ int lcnt, lbase;
  __shared__ ull lbuf[2048]; // block covers <=2048 anchors
  int b = blockIdx.y;
  int t = tsel[b];
  if (threadIdx.x == 0) lcnt = 0;
  __syncthreads();
  const float2* p = probs + (size_t)b * NA;
  for (int a = blockIdx.x * blockDim.x + threadIdx.x; a < NA; a += gridDim.x * blockDim.x) {
    float s = p[a].y;
    if (score_bin(s) >= t) {
      int pos = atomicAdd(&lcnt, 1);
      unsigned int ib = ~__float_as_uint(s); // score>=0: ~bits ascending == score descending
      lbuf[pos] = ((ull)ib << 32) | (unsigned int)a;
    }
  }
  __syncthreads();
  if (threadIdx.x == 0) lbase = atomicAdd(&cnt[b * 16], lcnt);
  __syncthreads();
  int n = lcnt, base = lbase;
  ull* kb = keys + (size_t)b * CAP;
  for (int i = threadIdx.x; i < n; i += 256) {
    int pos = base + i;
    if (pos < CAP) kb[pos] = lbuf[i];
  }
}

// ---------------- 4. bitonic sort + box decode ----------------
__global__ __launch_bounds__(1024) void sortbox_kernel(const float4* __restrict__ anchors4,
                                                       const float4* __restrict__ bbox4,
                                                       const int* __restrict__ cnt,
                                                       const ull* __restrict__ keys,
                                                       float4* __restrict__ boxes4) {
#pragma clang fp contract(off)
  __shared__ ull sh[CAP];
  int b = blockIdx.x;
  int n = cnt[b * 16];
  if (n > CAP) n = CAP;
  const ull* kb = keys + (size_t)b * CAP;
  for (int i = threadIdx.x; i < CAP; i += 1024) sh[i] = (i < n) ? kb[i] : ~0ull;
  __syncthreads();
  for (int k = 2; k <= CAP; k <<= 1) {
    for (int j = k >> 1; j > 0; j >>= 1) {
      for (int i = threadIdx.x; i < CAP; i += 1024) {
        int ixj = i ^ j;
        if (ixj > i) {
          ull a = sh[i], c = sh[ixj];
          bool up = ((i & k) == 0);
          if ((a > c) == up) { sh[i] = c; sh[ixj] = a; }
        }
      }
      __syncthreads();
    }
  }
  for (int r = threadIdx.x; r < KSEL; r += 1024) {
    int a = (int)(unsigned int)sh[r];
    float4 anc = anchors4[(size_t)b * NA + a];
    float4 d   = bbox4[(size_t)b * NA + a];
    float h = anc.z - anc.x;
    float w = anc.w - anc.y;
    float dy = d.x * 0.1f, dx = d.y * 0.1f, dh = d.z * 0.2f, dw = d.w * 0.2f;
    float cy = (anc.x + (0.5f * h)) + (dy * h);
    float cx = (anc.y + (0.5f * w)) + (dx * w);
    float h2 = h * expf(dh);
    float w2 = w * expf(dw);
    float y1 = cy - 0.5f * h2;
    float x1 = cx - 0.5f * w2;
    float y2 = y1 + h2;
    float x2 = x1 + w2;
    y1 = fminf(fmaxf(y1, 0.f), 1.f);
    x1 = fminf(fmaxf(x1, 0.f), 1.f);
    y2 = fminf(fmaxf(y2, 0.f), 1.f);
    x2 = fminf(fmaxf(x2, 0.f), 1.f);
    boxes4[(size_t)b * KSEL + r] = make_float4(y1, x1, y2, x2);
  }
}

// ---------------- 5. suppression mask, ROW-major [b][row][96] words ----------------
// grid (24, NB, BATCH), block = 4 waves. Block covers rows rb*64..+63, words cb0..cb0+3,
// cb0 = rb + 4*cx  (only upper-triangle words ever written; words<rb stay poison and are
// excluded in scan; pad words 94/95 written as zeros).
// Divide-free IoU test with exact guard band: |inter-0.7*uni| > 6e-7*uni decides by sign,
// else exact IEEE division (rare).
__global__ __launch_bounds__(256) void mask_kernel(const float4* __restrict__ boxes4,
                                                   ull* __restrict__ mask) {
  int cx = blockIdx.x, rb = blockIdx.y, b = blockIdx.z;
  int cb0 = rb + 4 * cx;
  if (cb0 >= NWP) return;
  __shared__ float4 colbox[4][64];
  __shared__ ull wtile[64][5];      // pad 5 -> minor conflicts only
  int tid = threadIdx.x, wv = tid >> 6, l = tid & 63;
  int cb = cb0 + wv;
  int row = rb * 64 + l;
  float4 r = (row < KSEL) ? boxes4[(size_t)b * KSEL + row] : make_float4(0.f, 0.f, 0.f, 0.f);
  float ra = (r.z - r.x) * (r.w - r.y);
  int c = cb * 64 + l;
  colbox[wv][l] = (cb < NB && c < KSEL) ? boxes4[(size_t)b * KSEL + c]
                                        : make_float4(0.f, 0.f, 0.f, 0.f);
  __syncthreads();
  ull bits = 0ull;
  if (cb < NB) {
#pragma unroll
    for (int u = 0; u < 64; ++u) {
      float4 cbx = colbox[wv][u];
      float ca = (cbx.z - cbx.x) * (cbx.w - cbx.y);
      float ih = fmaxf(fminf(r.z, cbx.z) - fmaxf(r.x, cbx.x), 0.f);
      float iw = fmaxf(fminf(r.w, cbx.w) - fmaxf(r.y, cbx.y), 0.f);
      float inter = ih * iw;
      float uni = (ra + ca) - inter;
      float d = inter - 0.7f * uni;
      float tt = 6e-7f * uni;
      bool keep;
      if (__builtin_fabsf(d) <= tt) {
        keep = (inter / uni) > 0.7f;   // exact tie-region path (rare; NaN for 0/0 -> false)
      } else {
        keep = d > 0.f;
      }
      if (keep) bits |= (1ull << u);
    }
    if (cb == rb) {
      // zero bits for cc <= row (order > i condition); l==63 -> all zero
      bits &= (l == 63) ? 0ull : (~0ull << (l + 1));
    }
  }
  wtile[l][wv] = bits;
  __syncthreads();
  int nrows = min(64, KSEL - rb * 64);
  int rr = tid >> 2, w = tid & 3;
  if (rr < nrows)
    mask[((size_t)b * KSEL + (size_t)(rb * 64 + rr)) * NWP + cb0 + w] = wtile[rr][w];
}

// ---------------- 6. single-wave greedy scan, all state in registers ----------------
// lane l holds words 2l,2l+1 of the suppressed-bitmap (Sx,Sy) and each prefetched row.
// Words below a kept row's own word index are unwritten (poison) -> excluded by cndmask.
__global__ __launch_bounds__(64, 1) void scan_kernel(const float4* __restrict__ boxes4,
                                                     const ull* __restrict__ mask,
                                                     float4* __restrict__ out4) {
  __shared__ int skeep[PROP];
  int b = blockIdx.x;
  int lane = threadIdx.x;
  const ull* mb = mask + (size_t)b * KSEL * NWP;
  int col = (2 * lane < NB) ? 2 * lane : NB;   // lanes >=47 read pad words 94,95 (zeros)
  int wx = 2 * lane, wy = 2 * lane + 1;        // nominal word indices held by this lane

  ulonglong2 r[32];                 // 32-row prefetch ring, statically indexed
#pragma unroll
  for (int k = 0; k < 32; ++k)
    r[k] = *(const ulonglong2*)(mb + (size_t)k * NWP + col);

  ull Sx = 0ull, Sy = 0ull;         // suppressed words 2*lane, 2*lane+1
  int kept = 0;
  bool done = false;

  for (int i0 = 0; i0 < KSEL && !done; i0 += 64) {
    int w  = i0 >> 6;               // uniform: same word for all 64 rows of this block
    int ol = w >> 1;                // owner lane
    auto run = [&](bool useY) {
#pragma unroll
      for (int u = 0; u < 64; ++u) {
        int i = i0 + u;
        if (i >= KSEL) { done = true; break; }
        ull Ssel = useY ? Sy : Sx;
        unsigned int piece = (u < 32) ? (unsigned int)Ssel : (unsigned int)(Ssel >> 32);
        unsigned int v = (unsigned int)__builtin_amdgcn_readlane((int)piece, ol);
        if (!((v >> (u & 31)) & 1u)) {
          if (lane == 0) skeep[kept] = i;
          ++kept;
          if (kept >= PROP) { done = true; break; }
          int wlim = i >> 6;        // words < wlim of row i are invalid (poison)
          Sx |= (wx >= wlim) ? r[u & 31].x : 0ull;
          Sy |= (wy >= wlim) ? r[u & 31].y : 0ull;
        }
        if (i + 32 < KSEL)
          r[u & 31] = *(const ulonglong2*)(mb + (size_t)(i + 32) * NWP + col);
      }
    };
    if ((w & 1) == 0) run(false); else run(true);
  }

  __syncthreads();
  int fin = kept;
  for (int rr = lane; rr < PROP; rr += 64) {
    float4 v = make_float4(0.f, 0.f, 0.f, 0.f);
    if (rr < fin) v = boxes4[(size_t)b * KSEL + skeep[rr]];
    out4[(size_t)b * PROP + rr] = v;
  }
}

// ---------------- launch ----------------
extern "C" void kernel_launch(void* const* d_in, const int* in_sizes, int n_in,
                              void* d_out, int out_size, void* d_ws, size_t ws_size,
                              hipStream_t stream) {
  const float2* probs   = (const float2*)d_in[0];
  const float4* bbox4   = (const float4*)d_in[1];
  const float4* anchors4= (const float4*)d_in[2];
  float4* out4 = (float4*)d_out;
  char* ws = (char*)d_ws;

  int* cnt      = (int*)(ws + OFF_CNT);
  int* tsel     = (int*)(ws + OFF_TSEL);
  float4* boxes4= (float4*)(ws + OFF_BOXES);
  ull* maskw    = (ull*)(ws + OFF_MASK);
  ull* keys     = (ull*)(ws + OFF_KEYS);   // aliases mask head
  unsigned int* hist = (unsigned int*)(ws + OFF_HIST); // aliases mask head

  hipMemsetAsync(ws + OFF_CNT, 0, 544, stream);

  hipLaunchKernelGGL(hist_kernel,    dim3(HB, BATCH),   dim3(256),  0, stream, probs, hist);
  hipLaunchKernelGGL(thresh_kernel,  dim3(BATCH),       dim3(256),  0, stream, hist, tsel);
  hipLaunchKernelGGL(compact_kernel, dim3(128, BATCH),  dim3(256),  0, stream, probs, tsel, cnt, keys);
  hipLaunchKernelGGL(sortbox_kernel, dim3(BATCH),       dim3(1024), 0, stream, anchors4, bbox4, cnt, keys, boxes4);
  hipLaunchKernelGGL(mask_kernel,    dim3(24, NB, BATCH), dim3(256), 0, stream, boxes4, maskw);
  hipLaunchKernelGGL(scan_kernel,    dim3(BATCH),       dim3(64),   0, stream, boxes4, maskw, out4);
}

// Round 7
// 474.410 us; speedup vs baseline: 1.2929x; 1.0217x over previous
//
#include <hip/hip_runtime.h>
#include <hip/hip_bf16.h>

typedef unsigned long long ull;

// ---------------- problem constants ----------------
constexpr int BATCH = 8;
constexpr int NA    = 261888;
constexpr int KSEL  = 6000;          // PRE_NMS_LIMIT
constexpr int PROP  = 1000;          // PROPOSAL_COUNT
constexpr int CAP   = 8192;          // candidate capacity (pow2 for bitonic)
constexpr int NBINS = 8192;          // histogram bins
constexpr int HB    = 16;            // private histogram blocks per batch
constexpr int NB    = (KSEL + 63) / 64;   // 94 mask words per row
constexpr int NWP   = 96;            // padded words per row (96*8 = 768B rows)
constexpr int NBLK  = (KSEL + 63) / 64;   // 94 row-blocks

// workspace layout (bytes). keys and hist BOTH alias the mask head (disjoint liveness).
constexpr size_t OFF_CNT   = 0;                       // 8*16*4 = 512
constexpr size_t OFF_TSEL  = 512;                     // 32
constexpr size_t OFF_BOXES = 544;                     // 8*6000*16 = 768000
constexpr size_t OFF_MASK  = 769024;                  // 8*6000*96*8 = 36864000
constexpr size_t OFF_KEYS  = OFF_MASK;                // 524288 (aliased)
constexpr size_t OFF_HIST  = OFF_MASK;                // 4MB (aliased)
// total = 37,633,024 B

__device__ __forceinline__ int score_bin(float s) {
  int b = (int)(s * (float)NBINS);
  if (b < 0) b = 0;
  if (b > NBINS - 1) b = NBINS - 1;
  return b;
}

// ---------------- 1. histogram (private per-block copies, no global atomics) ----------------
__global__ __launch_bounds__(256) void hist_kernel(const float2* __restrict__ probs,
                                                   unsigned int* __restrict__ hist) {
  __shared__ unsigned int lh[NBINS];
  for (int i = threadIdx.x; i < NBINS; i += 256) lh[i] = 0u;
  __syncthreads();
  int b = blockIdx.y;
  const float2* p = probs + (size_t)b * NA;
  for (int a = blockIdx.x * 256 + threadIdx.x; a < NA; a += HB * 256) {
    atomicAdd(&lh[score_bin(p[a].y)], 1u);
  }
  __syncthreads();
  unsigned int* gh = hist + ((size_t)b * HB + blockIdx.x) * NBINS;
  for (int i = threadIdx.x; i < NBINS; i += 256) gh[i] = lh[i];
}

// ---------------- 2. threshold bin select ----------------
__global__ __launch_bounds__(256) void thresh_kernel(const unsigned int* __restrict__ hist,
                                                     int* __restrict__ tsel) {
  constexpr int GR = NBINS / 256; // 32 bins per thread
  __shared__ unsigned int ch[NBINS];
  __shared__ unsigned int gsum[256];
  int b = blockIdx.x;
  const unsigned int* h = hist + (size_t)b * HB * NBINS;
  for (int bin = threadIdx.x; bin < NBINS; bin += 256) {
    unsigned int s = 0;
    for (int k = 0; k < HB; ++k) s += h[(size_t)k * NBINS + bin];
    ch[bin] = s;
  }
  __syncthreads();
  unsigned int s = 0;
  int g0 = threadIdx.x * GR;
  for (int i = 0; i < GR; ++i) s += ch[g0 + i];
  gsum[threadIdx.x] = s;
  __syncthreads();
  if (threadIdx.x == 0) {
    unsigned int acc = 0;
    int g = 255;
    for (; g > 0; --g) {
      if (acc + gsum[g] >= (unsigned)KSEL) break;
      acc += gsum[g];
    }
    int t = g * GR;
    for (int bin = g * GR + GR - 1; bin >= g * GR; --bin) {
      acc += ch[bin];
      if (acc >= (unsigned)KSEL) { t = bin; break; }
    }
    tsel[b] = t;
  }
}

// ---------------- 3. compact candidates (block-aggregated, 1 global atomic/block) ----------------
__global__ __launch_bounds__(256) void compact_kernel(const float2* __restrict__ probs,
                                                      const int* __restrict__ tsel,
                                                      int* __restrict__ cnt,
                                                      ull* __restrict__ keys) {
  __shared__ int lcnt, lbase;
  __shared__ ull lbuf[2048]; // block covers <=2048 anchors
  int b = blockIdx.y;
  int t = tsel[b];
  if (threadIdx.x == 0) lcnt = 0;
  __syncthreads();
  const float2* p = probs + (size_t)b * NA;
  for (int a = blockIdx.x * blockDim.x + threadIdx.x; a < NA; a += gridDim.x * blockDim.x) {
    float s = p[a].y;
    if (score_bin(s) >= t) {
      int pos = atomicAdd(&lcnt, 1);
      unsigned int ib = ~__float_as_uint(s); // score>=0: ~bits ascending == score descending
      lbuf[pos] = ((ull)ib << 32) | (unsigned int)a;
    }
  }
  __syncthreads();
  if (threadIdx.x == 0) lbase = atomicAdd(&cnt[b * 16], lcnt);
  __syncthreads();
  int n = lcnt, base = lbase;
  ull* kb = keys + (size_t)b * CAP;
  for (int i = threadIdx.x; i < n; i += 256) {
    int pos = base + i;
    if (pos < CAP) kb[pos] = lbuf[i];
  }
}

// ---------------- 4. bitonic sort + box decode ----------------
__global__ __launch_bounds__(1024) void sortbox_kernel(const float4* __restrict__ anchors4,
                                                       const float4* __restrict__ bbox4,
                                                       const int* __restrict__ cnt,
                                                       const ull* __restrict__ keys,
                                                       float4* __restrict__ boxes4) {
#pragma clang fp contract(off)
  __shared__ ull sh[CAP];
  int b = blockIdx.x;
  int n = cnt[b * 16];
  if (n > CAP) n = CAP;
  const ull* kb = keys + (size_t)b * CAP;
  for (int i = threadIdx.x; i < CAP; i += 1024) sh[i] = (i < n) ? kb[i] : ~0ull;
  __syncthreads();
  for (int k = 2; k <= CAP; k <<= 1) {
    for (int j = k >> 1; j > 0; j >>= 1) {
      for (int i = threadIdx.x; i < CAP; i += 1024) {
        int ixj = i ^ j;
        if (ixj > i) {
          ull a = sh[i], c = sh[ixj];
          bool up = ((i & k) == 0);
          if ((a > c) == up) { sh[i] = c; sh[ixj] = a; }
        }
      }
      __syncthreads();
    }
  }
  for (int r = threadIdx.x; r < KSEL; r += 1024) {
    int a = (int)(unsigned int)sh[r];
    float4 anc = anchors4[(size_t)b * NA + a];
    float4 d   = bbox4[(size_t)b * NA + a];
    float h = anc.z - anc.x;
    float w = anc.w - anc.y;
    float dy = d.x * 0.1f, dx = d.y * 0.1f, dh = d.z * 0.2f, dw = d.w * 0.2f;
    float cy = (anc.x + (0.5f * h)) + (dy * h);
    float cx = (anc.y + (0.5f * w)) + (dx * w);
    float h2 = h * expf(dh);
    float w2 = w * expf(dw);
    float y1 = cy - 0.5f * h2;
    float x1 = cx - 0.5f * w2;
    float y2 = y1 + h2;
    float x2 = x1 + w2;
    y1 = fminf(fmaxf(y1, 0.f), 1.f);
    x1 = fminf(fmaxf(x1, 0.f), 1.f);
    y2 = fminf(fmaxf(y2, 0.f), 1.f);
    x2 = fminf(fmaxf(x2, 0.f), 1.f);
    boxes4[(size_t)b * KSEL + r] = make_float4(y1, x1, y2, x2);
  }
}

// ---------------- 5. suppression mask, ROW-major [b][row][96] words ----------------
// grid (24, NB, BATCH), block = 4 waves. Block covers rows rb*64..+63, words cb0..cb0+3,
// cb0 = rb + 4*cx. Only upper-triangle words written; words<rb stay poison (never read);
// pad words >= NB written as zeros.
__global__ __launch_bounds__(256) void mask_kernel(const float4* __restrict__ boxes4,
                                                   ull* __restrict__ mask) {
  int cx = blockIdx.x, rb = blockIdx.y, b = blockIdx.z;
  int cb0 = rb + 4 * cx;
  if (cb0 >= NWP) return;
  __shared__ float4 colbox[4][64];
  __shared__ ull wtile[64][5];
  int tid = threadIdx.x, wv = tid >> 6, l = tid & 63;
  int cb = cb0 + wv;
  int row = rb * 64 + l;
  float4 r = (row < KSEL) ? boxes4[(size_t)b * KSEL + row] : make_float4(0.f, 0.f, 0.f, 0.f);
  float ra = (r.z - r.x) * (r.w - r.y);
  int c = cb * 64 + l;
  colbox[wv][l] = (cb < NB && c < KSEL) ? boxes4[(size_t)b * KSEL + c]
                                        : make_float4(0.f, 0.f, 0.f, 0.f);
  __syncthreads();
  ull bits = 0ull;
  if (cb < NB) {
#pragma unroll
    for (int u = 0; u < 64; ++u) {
      float4 cbx = colbox[wv][u];
      float ca = (cbx.z - cbx.x) * (cbx.w - cbx.y);
      float ih = fmaxf(fminf(r.z, cbx.z) - fmaxf(r.x, cbx.x), 0.f);
      float iw = fmaxf(fminf(r.w, cbx.w) - fmaxf(r.y, cbx.y), 0.f);
      float inter = ih * iw;
      float uni = (ra + ca) - inter;
      float d = inter - 0.7f * uni;
      float tt = 6e-7f * uni;
      bool keep;
      if (__builtin_fabsf(d) <= tt) {
        keep = (inter / uni) > 0.7f;   // exact tie-region path (rare; NaN for 0/0 -> false)
      } else {
        keep = d > 0.f;
      }
      if (keep) bits |= (1ull << u);
    }
    if (cb == rb) {
      bits &= (l == 63) ? 0ull : (~0ull << (l + 1)); // only cc > row suppress
    }
  }
  wtile[l][wv] = bits;
  __syncthreads();
  int nrows = min(64, KSEL - rb * 64);
  int rr = tid >> 2, w = tid & 3;
  if (rr < nrows)
    mask[((size_t)b * KSEL + (size_t)(rb * 64 + rr)) * NWP + cb0 + w] = wtile[rr][w];
}

// ---------------- 6. single-wave block-scalar greedy scan ----------------
// Per 64-row block: diag word per lane (1 load, double-buffered), SALU greedy via
// s_ff1 + readlane (suppressed rows cost zero), then OR kept rows' full masks into
// the lane-distributed suppressed bitmap with 16-deep batched loads.
// Poison words (below each row's diagonal) are only ever ORed into S-words that have
// already been consumed -> never affect a decision.
__global__ __launch_bounds__(64, 1) void scan_kernel(const float4* __restrict__ boxes4,
                                                     const ull* __restrict__ mask,
                                                     float4* __restrict__ out4) {
  __shared__ int skeep[PROP];
  int b = blockIdx.x;
  int lane = threadIdx.x;
  const ull* mb = mask + (size_t)b * KSEL * NWP;
  int col = (2 * lane < NB) ? 2 * lane : NB;   // lanes >=47 -> pad words 94,95 (zeros)

  ull Sx = 0ull, Sy = 0ull;                    // suppressed words 2*lane, 2*lane+1
  int kept = 0;
  bool done = false;

  int r0 = (lane < KSEL) ? lane : (KSEL - 1);
  ull dg = mb[(size_t)r0 * NWP + 0];           // block 0 diagonal word

  for (int n = 0; n < NBLK && !done; ++n) {
    int i0 = n * 64;
    // prefetch next block's diagonal word
    ull dgN = 0ull;
    if (n + 1 < NBLK) {
      int rn = (n + 1) * 64 + lane;
      if (rn >= KSEL) rn = KSEL - 1;
      dgN = mb[(size_t)rn * NWP + (n + 1)];
    }
    // current suppression word for this block (word n lives in lane n>>1)
    int ol = n >> 1;
    ull Ssel = (n & 1) ? Sy : Sx;
    unsigned slo = (unsigned)__builtin_amdgcn_readlane((int)(unsigned)Ssel, ol);
    unsigned shi = (unsigned)__builtin_amdgcn_readlane((int)(unsigned)(Ssel >> 32), ol);
    ull Sw = (ull)slo | ((ull)shi << 32);

    int nval = KSEL - i0;
    ull valid = (nval >= 64) ? ~0ull : ((1ull << nval) - 1ull);
    ull A = ~Sw & valid;
    ull K = 0ull;
    unsigned vlo = (unsigned)dg, vhi = (unsigned)(dg >> 32);

    while (A) {
      int u = __builtin_ctzll(A);
      if (lane == 0) skeep[kept] = i0 + u;
      ++kept;
      K |= (1ull << u);
      if (kept >= PROP) { done = true; break; }
      ull Mu = (ull)(unsigned)__builtin_amdgcn_readlane((int)vlo, u)
             | ((ull)(unsigned)__builtin_amdgcn_readlane((int)vhi, u) << 32);
      A &= ~(Mu | (1ull << u));
    }

    if (!done) {
      // OR full masks of kept rows into distributed S, 16 loads in flight
      ull kk = K;
      while (kk) {
        ull tx[16], ty[16];
        int us[16];
#pragma unroll
        for (int j = 0; j < 16; ++j) {
          int u = (kk != 0ull) ? __builtin_ctzll(kk) : -1;
          kk &= (kk - 1ull);                    // 0 stays 0
          us[j] = u;
          int ur = i0 + ((u >= 0) ? u : 0);
          const ull* p = mb + (size_t)ur * NWP + col;
          tx[j] = p[0];
          ty[j] = p[1];
        }
#pragma unroll
        for (int j = 0; j < 16; ++j) {
          if (us[j] >= 0) { Sx |= tx[j]; Sy |= ty[j]; }
        }
      }
    }
    dg = dgN;
  }

  __syncthreads();
  int fin = kept;
  for (int rr = lane; rr < PROP; rr += 64) {
    float4 v = make_float4(0.f, 0.f, 0.f, 0.f);
    if (rr < fin) v = boxes4[(size_t)b * KSEL + skeep[rr]];
    out4[(size_t)b * PROP + rr] = v;
  }
}

// ---------------- launch ----------------
extern "C" void kernel_launch(void* const* d_in, const int* in_sizes, int n_in,
                              void* d_out, int out_size, void* d_ws, size_t ws_size,
                              hipStream_t stream) {
  const float2* probs   = (const float2*)d_in[0];
  const float4* bbox4   = (const float4*)d_in[1];
  const float4* anchors4= (const float4*)d_in[2];
  float4* out4 = (float4*)d_out;
  char* ws = (char*)d_ws;

  int* cnt      = (int*)(ws + OFF_CNT);
  int* tsel     = (int*)(ws + OFF_TSEL);
  float4* boxes4= (float4*)(ws + OFF_BOXES);
  ull* maskw    = (ull*)(ws + OFF_MASK);
  ull* keys     = (ull*)(ws + OFF_KEYS);   // aliases mask head
  unsigned int* hist = (unsigned int*)(ws + OFF_HIST); // aliases mask head

  hipMemsetAsync(ws + OFF_CNT, 0, 544, stream);

  hipLaunchKernelGGL(hist_kernel,    dim3(HB, BATCH),   dim3(256),  0, stream, probs, hist);
  hipLaunchKernelGGL(thresh_kernel,  dim3(BATCH),       dim3(256),  0, stream, hist, tsel);
  hipLaunchKernelGGL(compact_kernel, dim3(128, BATCH),  dim3(256),  0, stream, probs, tsel, cnt, keys);
  hipLaunchKernelGGL(sortbox_kernel, dim3(BATCH),       dim3(1024), 0, stream, anchors4, bbox4, cnt, keys, boxes4);
  hipLaunchKernelGGL(mask_kernel,    dim3(24, NB, BATCH), dim3(256), 0, stream, boxes4, maskw);
  hipLaunchKernelGGL(scan_kernel,    dim3(BATCH),       dim3(64),   0, stream, boxes4, maskw, out4);
}

// Round 8
// 413.081 us; speedup vs baseline: 1.4849x; 1.1485x over previous
//
#include <hip/hip_runtime.h>
#include <hip/hip_bf16.h>

typedef unsigned long long ull;

// ---------------- problem constants ----------------
constexpr int BATCH = 8;
constexpr int NA    = 261888;
constexpr int KSEL  = 6000;          // PRE_NMS_LIMIT
constexpr int PROP  = 1000;          // PROPOSAL_COUNT
constexpr int CAP   = 8192;          // candidate capacity (pow2 for bitonic)
constexpr int NBINS = 8192;          // histogram bins
constexpr int HB    = 16;            // private histogram blocks per batch
constexpr int NB    = (KSEL + 63) / 64;   // 94 mask words per row
constexpr int NWP   = 96;            // padded words per row (96*8 = 768B rows)
constexpr int NBLK  = (KSEL + 63) / 64;   // 94 row-blocks

// workspace layout (bytes). keys and hist BOTH alias the mask head (disjoint liveness).
constexpr size_t OFF_CNT   = 0;                       // 8*16*4 = 512
constexpr size_t OFF_TSEL  = 512;                     // 32
constexpr size_t OFF_BOXES = 544;                     // 8*6000*16 = 768000
constexpr size_t OFF_MASK  = 769024;                  // 8*6000*96*8 = 36864000
constexpr size_t OFF_KEYS  = OFF_MASK;                // 524288 (aliased)
constexpr size_t OFF_HIST  = OFF_MASK;                // 4MB (aliased)
// total = 37,633,024 B

__device__ __forceinline__ int score_bin(float s) {
  int b = (int)(s * (float)NBINS);
  if (b < 0) b = 0;
  if (b > NBINS - 1) b = NBINS - 1;
  return b;
}

// ---------------- 1. histogram (private per-block copies, no global atomics) ----------------
__global__ __launch_bounds__(256) void hist_kernel(const float2* __restrict__ probs,
                                                   unsigned int* __restrict__ hist) {
  __shared__ unsigned int lh[NBINS];
  for (int i = threadIdx.x; i < NBINS; i += 256) lh[i] = 0u;
  __syncthreads();
  int b = blockIdx.y;
  const float2* p = probs + (size_t)b * NA;
  for (int a = blockIdx.x * 256 + threadIdx.x; a < NA; a += HB * 256) {
    atomicAdd(&lh[score_bin(p[a].y)], 1u);
  }
  __syncthreads();
  unsigned int* gh = hist + ((size_t)b * HB + blockIdx.x) * NBINS;
  for (int i = threadIdx.x; i < NBINS; i += 256) gh[i] = lh[i];
}

// ---------------- 2. threshold bin select ----------------
__global__ __launch_bounds__(256) void thresh_kernel(const unsigned int* __restrict__ hist,
                                                     int* __restrict__ tsel) {
  constexpr int GR = NBINS / 256; // 32 bins per thread
  __shared__ unsigned int ch[NBINS];
  __shared__ unsigned int gsum[256];
  int b = blockIdx.x;
  const unsigned int* h = hist + (size_t)b * HB * NBINS;
  for (int bin = threadIdx.x; bin < NBINS; bin += 256) {
    unsigned int s = 0;
    for (int k = 0; k < HB; ++k) s += h[(size_t)k * NBINS + bin];
    ch[bin] = s;
  }
  __syncthreads();
  unsigned int s = 0;
  int g0 = threadIdx.x * GR;
  for (int i = 0; i < GR; ++i) s += ch[g0 + i];
  gsum[threadIdx.x] = s;
  __syncthreads();
  if (threadIdx.x == 0) {
    unsigned int acc = 0;
    int g = 255;
    for (; g > 0; --g) {
      if (acc + gsum[g] >= (unsigned)KSEL) break;
      acc += gsum[g];
    }
    int t = g * GR;
    for (int bin = g * GR + GR - 1; bin >= g * GR; --bin) {
      acc += ch[bin];
      if (acc >= (unsigned)KSEL) { t = bin; break; }
    }
    tsel[b] = t;
  }
}

// ---------------- 3. compact candidates (block-aggregated, 1 global atomic/block) ----------------
__global__ __launch_bounds__(256) void compact_kernel(const float2* __restrict__ probs,
                                                      const int* __restrict__ tsel,
                                                      int* __restrict__ cnt,
                                                      ull* __restrict__ keys) {
  __shared__ int lcnt, lbase;
  __shared__ ull lbuf[2048]; // block covers <=2048 anchors
  int b = blockIdx.y;
  int t = tsel[b];
  if (threadIdx.x == 0) lcnt = 0;
  __syncthreads();
  const float2* p = probs + (size_t)b * NA;
  for (int a = blockIdx.x * blockDim.x + threadIdx.x; a < NA; a += gridDim.x * blockDim.x) {
    float s = p[a].y;
    if (score_bin(s) >= t) {
      int pos = atomicAdd(&lcnt, 1);
      unsigned int ib = ~__float_as_uint(s); // score>=0: ~bits ascending == score descending
      lbuf[pos] = ((ull)ib << 32) | (unsigned int)a;
    }
  }
  __syncthreads();
  if (threadIdx.x == 0) lbase = atomicAdd(&cnt[b * 16], lcnt);
  __syncthreads();
  int n = lcnt, base = lbase;
  ull* kb = keys + (size_t)b * CAP;
  for (int i = threadIdx.x; i < n; i += 256) {
    int pos = base + i;
    if (pos < CAP) kb[pos] = lbuf[i];
  }
}

// ---------------- 4. bitonic sort + box decode ----------------
__global__ __launch_bounds__(1024) void sortbox_kernel(const float4* __restrict__ anchors4,
                                                       const float4* __restrict__ bbox4,
                                                       const int* __restrict__ cnt,
                                                       const ull* __restrict__ keys,
                                                       float4* __restrict__ boxes4) {
#pragma clang fp contract(off)
  __shared__ ull sh[CAP];
  int b = blockIdx.x;
  int n = cnt[b * 16];
  if (n > CAP) n = CAP;
  const ull* kb = keys + (size_t)b * CAP;
  for (int i = threadIdx.x; i < CAP; i += 1024) sh[i] = (i < n) ? kb[i] : ~0ull;
  __syncthreads();
  for (int k = 2; k <= CAP; k <<= 1) {
    for (int j = k >> 1; j > 0; j >>= 1) {
      for (int i = threadIdx.x; i < CAP; i += 1024) {
        int ixj = i ^ j;
        if (ixj > i) {
          ull a = sh[i], c = sh[ixj];
          bool up = ((i & k) == 0);
          if ((a > c) == up) { sh[i] = c; sh[ixj] = a; }
        }
      }
      __syncthreads();
    }
  }
  for (int r = threadIdx.x; r < KSEL; r += 1024) {
    int a = (int)(unsigned int)sh[r];
    float4 anc = anchors4[(size_t)b * NA + a];
    float4 d   = bbox4[(size_t)b * NA + a];
    float h = anc.z - anc.x;
    float w = anc.w - anc.y;
    float dy = d.x * 0.1f, dx = d.y * 0.1f, dh = d.z * 0.2f, dw = d.w * 0.2f;
    float cy = (anc.x + (0.5f * h)) + (dy * h);
    float cx = (anc.y + (0.5f * w)) + (dx * w);
    float h2 = h * expf(dh);
    float w2 = w * expf(dw);
    float y1 = cy - 0.5f * h2;
    float x1 = cx - 0.5f * w2;
    float y2 = y1 + h2;
    float x2 = x1 + w2;
    y1 = fminf(fmaxf(y1, 0.f), 1.f);
    x1 = fminf(fmaxf(x1, 0.f), 1.f);
    y2 = fminf(fmaxf(y2, 0.f), 1.f);
    x2 = fminf(fmaxf(x2, 0.f), 1.f);
    boxes4[(size_t)b * KSEL + r] = make_float4(y1, x1, y2, x2);
  }
}

// ---------------- 5. suppression mask, ROW-major [b][row][96] words ----------------
// grid (24, NB, BATCH), block = 4 waves. Block covers rows rb*64..+63, words cb0..cb0+3,
// cb0 = rb + 4*cx. Only upper-triangle words written; words<rb stay poison (never read);
// pad words >= NB written as zeros. Writes clamped to cb0+w < NWP (word 96 would alias
// the NEXT row's word 0 -> cross-batch race).
__global__ __launch_bounds__(256) void mask_kernel(const float4* __restrict__ boxes4,
                                                   ull* __restrict__ mask) {
  int cx = blockIdx.x, rb = blockIdx.y, b = blockIdx.z;
  int cb0 = rb + 4 * cx;
  if (cb0 >= NWP) return;
  __shared__ float4 colbox[4][64];
  __shared__ ull wtile[64][5];
  int tid = threadIdx.x, wv = tid >> 6, l = tid & 63;
  int cb = cb0 + wv;
  int row = rb * 64 + l;
  float4 r = (row < KSEL) ? boxes4[(size_t)b * KSEL + row] : make_float4(0.f, 0.f, 0.f, 0.f);
  float ra = (r.z - r.x) * (r.w - r.y);
  int c = cb * 64 + l;
  colbox[wv][l] = (cb < NB && c < KSEL) ? boxes4[(size_t)b * KSEL + c]
                                        : make_float4(0.f, 0.f, 0.f, 0.f);
  __syncthreads();
  ull bits = 0ull;
  if (cb < NB) {
#pragma unroll
    for (int u = 0; u < 64; ++u) {
      float4 cbx = colbox[wv][u];
      float ca = (cbx.z - cbx.x) * (cbx.w - cbx.y);
      float ih = fmaxf(fminf(r.z, cbx.z) - fmaxf(r.x, cbx.x), 0.f);
      float iw = fmaxf(fminf(r.w, cbx.w) - fmaxf(r.y, cbx.y), 0.f);
      float inter = ih * iw;
      float uni = (ra + ca) - inter;
      float d = inter - 0.7f * uni;
      float tt = 6e-7f * uni;
      bool keep;
      if (__builtin_fabsf(d) <= tt) {
        keep = (inter / uni) > 0.7f;   // exact tie-region path (rare; NaN for 0/0 -> false)
      } else {
        keep = d > 0.f;
      }
      if (keep) bits |= (1ull << u);
    }
    if (cb == rb) {
      bits &= (l == 63) ? 0ull : (~0ull << (l + 1)); // only cc > row suppress
    }
  }
  wtile[l][wv] = bits;
  __syncthreads();
  int nrows = min(64, KSEL - rb * 64);
  int rr = tid >> 2, w = tid & 3;
  if (rr < nrows && cb0 + w < NWP)
    mask[((size_t)b * KSEL + (size_t)(rb * 64 + rr)) * NWP + cb0 + w] = wtile[rr][w];
}

// ---------------- 6. single-wave block-scalar greedy scan ----------------
// Per 64-row block: (a) unconditionally load ALL 64 rows' two lane-words (rr[64],
// decision-INDEPENDENT -> latency hides under the SALU decision chain), (b) diag word
// prefetched one block ahead, (c) SALU greedy via ctz+readlane, (d) OR kept rows via
// wave-uniform SGPR masks (pure static VALU, nothing for the compiler to serialize).
// Poison words (below a row's diagonal) only ever OR into S-words already consumed.
__global__ __launch_bounds__(64, 1) void scan_kernel(const float4* __restrict__ boxes4,
                                                     const ull* __restrict__ mask,
                                                     float4* __restrict__ out4) {
  __shared__ int skeep[PROP];
  int b = blockIdx.x;
  int lane = threadIdx.x;
  const ull* mb = mask + (size_t)b * KSEL * NWP;
  int col = (2 * lane < NB) ? 2 * lane : NB;   // lanes >=47 -> pad words 94,95 (zeros)

  ull Sx = 0ull, Sy = 0ull;                    // suppressed words 2*lane, 2*lane+1
  int kept = 0;
  bool done = false;

  ull dg = mb[(size_t)lane * NWP + 0];         // block 0 diagonal word (row=lane)

  for (int n = 0; n < NBLK && !done; ++n) {
    int i0 = n * 64;
    // force completion of the previous diag prefetch here (it's long done) so the
    // capped-vmcnt wait for it never lands in the middle of this block's loads.
    asm volatile("" : : "v"(dg));

    // (a) issue all 64 row loads (addresses independent of decisions)
    ulonglong2 rr[64];
#pragma unroll
    for (int u = 0; u < 64; ++u) {
      int ur = i0 + u;
      ur = (ur < KSEL) ? ur : (KSEL - 1);
      rr[u] = *(const ulonglong2*)(mb + (size_t)ur * NWP + col);
    }
    // (b) issue next block's diagonal prefetch (issued last -> never waited early)
    ull dgN = 0ull;
    if (n + 1 < NBLK) {
      int rn = (n + 1) * 64 + lane;
      if (rn >= KSEL) rn = KSEL - 1;
      dgN = mb[(size_t)rn * NWP + (n + 1)];
    }

    // (c) scalar greedy decision for this block
    int ol = n >> 1;
    ull Ssel = (n & 1) ? Sy : Sx;
    unsigned slo = (unsigned)__builtin_amdgcn_readlane((int)(unsigned)Ssel, ol);
    unsigned shi = (unsigned)__builtin_amdgcn_readlane((int)(unsigned)(Ssel >> 32), ol);
    ull Sw = (ull)slo | ((ull)shi << 32);
    int nval = KSEL - i0;
    ull valid = (nval >= 64) ? ~0ull : ((1ull << nval) - 1ull);
    ull A = ~Sw & valid;
    ull K = 0ull;
    unsigned vlo = (unsigned)dg, vhi = (unsigned)(dg >> 32);

    while (A) {
      int u = __builtin_ctzll(A);
      if (lane == 0) skeep[kept] = i0 + u;
      ++kept;
      K |= (1ull << u);
      if (kept >= PROP) { done = true; break; }
      ull Mu = (ull)(unsigned)__builtin_amdgcn_readlane((int)vlo, u)
             | ((ull)(unsigned)__builtin_amdgcn_readlane((int)vhi, u) << 32);
      A &= ~(Mu | (1ull << u));
    }

    // (d) OR kept rows into distributed S with uniform SGPR masks
    if (!done) {
#pragma unroll
      for (int u = 0; u < 64; ++u) {
        ull msk = 0ull - ((K >> u) & 1ull);    // wave-uniform: all-ones or 0
        Sx |= rr[u].x & msk;
        Sy |= rr[u].y & msk;
      }
    }
    dg = dgN;
  }

  __syncthreads();
  int fin = kept;
  for (int rr2 = lane; rr2 < PROP; rr2 += 64) {
    float4 v = make_float4(0.f, 0.f, 0.f, 0.f);
    if (rr2 < fin) v = boxes4[(size_t)b * KSEL + skeep[rr2]];
    out4[(size_t)b * PROP + rr2] = v;
  }
}

// ---------------- launch ----------------
extern "C" void kernel_launch(void* const* d_in, const int* in_sizes, int n_in,
                              void* d_out, int out_size, void* d_ws, size_t ws_size,
                              hipStream_t stream) {
  const float2* probs   = (const float2*)d_in[0];
  const float4* bbox4   = (const float4*)d_in[1];
  const float4* anchors4= (const float4*)d_in[2];
  float4* out4 = (float4*)d_out;
  char* ws = (char*)d_ws;

  int* cnt      = (int*)(ws + OFF_CNT);
  int* tsel     = (int*)(ws + OFF_TSEL);
  float4* boxes4= (float4*)(ws + OFF_BOXES);
  ull* maskw    = (ull*)(ws + OFF_MASK);
  ull* keys     = (ull*)(ws + OFF_KEYS);   // aliases mask head
  unsigned int* hist = (unsigned int*)(ws + OFF_HIST); // aliases mask head

  hipMemsetAsync(ws + OFF_CNT, 0, 544, stream);

  hipLaunchKernelGGL(hist_kernel,    dim3(HB, BATCH),   dim3(256),  0, stream, probs, hist);
  hipLaunchKernelGGL(thresh_kernel,  dim3(BATCH),       dim3(256),  0, stream, hist, tsel);
  hipLaunchKernelGGL(compact_kernel, dim3(128, BATCH),  dim3(256),  0, stream, probs, tsel, cnt, keys);
  hipLaunchKernelGGL(sortbox_kernel, dim3(BATCH),       dim3(1024), 0, stream, anchors4, bbox4, cnt, keys, boxes4);
  hipLaunchKernelGGL(mask_kernel,    dim3(24, NB, BATCH), dim3(256), 0, stream, boxes4, maskw);
  hipLaunchKernelGGL(scan_kernel,    dim3(BATCH),       dim3(64),   0, stream, boxes4, maskw, out4);
}

// Round 9
// 372.957 us; speedup vs baseline: 1.6446x; 1.1076x over previous
//
#include <hip/hip_runtime.h>
#include <hip/hip_bf16.h>

typedef unsigned long long ull;

// ---------------- problem constants ----------------
constexpr int BATCH = 8;
constexpr int NA    = 261888;
constexpr int KSEL  = 6000;          // PRE_NMS_LIMIT
constexpr int PROP  = 1000;          // PROPOSAL_COUNT
constexpr int CAP   = 8192;          // candidate capacity
constexpr int NBINS = 8192;          // histogram bins
constexpr int HB    = 16;            // private histogram blocks per batch
constexpr int NB    = (KSEL + 63) / 64;   // 94 mask words per row
constexpr int NWP   = 96;            // padded words per row (96*8 = 768B rows)
constexpr int NBLK  = (KSEL + 63) / 64;   // 94 row-blocks

// workspace layout (bytes). keys/rank/hist all live in the (later) mask region,
// at non-overlapping offsets; all die before mask_kernel writes.
constexpr size_t OFF_CNT   = 0;                       // 8*16*4 = 512
constexpr size_t OFF_TSEL  = 512;                     // 32
constexpr size_t OFF_BOXES = 544;                     // 8*6000*16 = 768000
constexpr size_t OFF_MASK  = 769024;                  // 8*6000*96*8 = 36864000
constexpr size_t OFF_KEYS  = OFF_MASK;                // 8*8192*8 = 524288
constexpr size_t OFF_RANK  = OFF_MASK + 524288;       // 8*8192*4 = 262144
constexpr size_t OFF_HIST  = OFF_MASK + 2097152;      // 4MB
// total = 37,633,024 B

__device__ __forceinline__ int score_bin(float s) {
  int b = (int)(s * (float)NBINS);
  if (b < 0) b = 0;
  if (b > NBINS - 1) b = NBINS - 1;
  return b;
}

// ---------------- 1. histogram (private per-block copies, no global atomics) ----------------
__global__ __launch_bounds__(256) void hist_kernel(const float2* __restrict__ probs,
                                                   unsigned int* __restrict__ hist) {
  __shared__ unsigned int lh[NBINS];
  for (int i = threadIdx.x; i < NBINS; i += 256) lh[i] = 0u;
  __syncthreads();
  int b = blockIdx.y;
  const float2* p = probs + (size_t)b * NA;
  for (int a = blockIdx.x * 256 + threadIdx.x; a < NA; a += HB * 256) {
    atomicAdd(&lh[score_bin(p[a].y)], 1u);
  }
  __syncthreads();
  unsigned int* gh = hist + ((size_t)b * HB + blockIdx.x) * NBINS;
  for (int i = threadIdx.x; i < NBINS; i += 256) gh[i] = lh[i];
}

// ---------------- 2. threshold bin select ----------------
__global__ __launch_bounds__(256) void thresh_kernel(const unsigned int* __restrict__ hist,
                                                     int* __restrict__ tsel) {
  constexpr int GR = NBINS / 256; // 32 bins per thread
  __shared__ unsigned int ch[NBINS];
  __shared__ unsigned int gsum[256];
  int b = blockIdx.x;
  const unsigned int* h = hist + (size_t)b * HB * NBINS;
  for (int bin = threadIdx.x; bin < NBINS; bin += 256) {
    unsigned int s = 0;
    for (int k = 0; k < HB; ++k) s += h[(size_t)k * NBINS + bin];
    ch[bin] = s;
  }
  __syncthreads();
  unsigned int s = 0;
  int g0 = threadIdx.x * GR;
  for (int i = 0; i < GR; ++i) s += ch[g0 + i];
  gsum[threadIdx.x] = s;
  __syncthreads();
  if (threadIdx.x == 0) {
    unsigned int acc = 0;
    int g = 255;
    for (; g > 0; --g) {
      if (acc + gsum[g] >= (unsigned)KSEL) break;
      acc += gsum[g];
    }
    int t = g * GR;
    for (int bin = g * GR + GR - 1; bin >= g * GR; --bin) {
      acc += ch[bin];
      if (acc >= (unsigned)KSEL) { t = bin; break; }
    }
    tsel[b] = t;
  }
}

// ---------------- 3. compact candidates (block-aggregated, 1 global atomic/block) ----------------
__global__ __launch_bounds__(256) void compact_kernel(const float2* __restrict__ probs,
                                                      const int* __restrict__ tsel,
                                                      int* __restrict__ cnt,
                                                      ull* __restrict__ keys) {
  __shared__ int lcnt, lbase;
  __shared__ ull lbuf[2048]; // block covers <=2048 anchors
  int b = blockIdx.y;
  int t = tsel[b];
  if (threadIdx.x == 0) lcnt = 0;
  __syncthreads();
  const float2* p = probs + (size_t)b * NA;
  for (int a = blockIdx.x * blockDim.x + threadIdx.x; a < NA; a += gridDim.x * blockDim.x) {
    float s = p[a].y;
    if (score_bin(s) >= t) {
      int pos = atomicAdd(&lcnt, 1);
      unsigned int ib = ~__float_as_uint(s); // score>=0: ~bits ascending == score descending
      lbuf[pos] = ((ull)ib << 32) | (unsigned int)a;
    }
  }
  __syncthreads();
  if (threadIdx.x == 0) lbase = atomicAdd(&cnt[b * 16], lcnt);
  __syncthreads();
  int n = lcnt, base = lbase;
  ull* kb = keys + (size_t)b * CAP;
  for (int i = threadIdx.x; i < n; i += 256) {
    int pos = base + i;
    if (pos < CAP) kb[pos] = lbuf[i];
  }
}

// ---------------- 4a. rank by counting (replaces bitonic sort) ----------------
// grid (32, 2, BATCH) x 256: thread owns key i = bx*256+tid; scans a j-half of the
// wave-uniform key stream (s_load batched; slots >= n are 0xFF.. = +inf, guard-free).
// rank[i] += #{ j in half : key_j < key_i }  via 2-way-contended atomicAdd.
__global__ __launch_bounds__(256) void rank_kernel(const int* __restrict__ cnt,
                                                   const ull* __restrict__ keys,
                                                   unsigned int* __restrict__ rank) {
  int b = blockIdx.z;
  int n = cnt[b * 16];
  if (n > CAP) n = CAP;
  int i = blockIdx.x * 256 + threadIdx.x;
  if (i >= n) return;
  const ull* kb = keys + (size_t)b * CAP;
  ull my = kb[i];
  int n16 = (n + 15) & ~15;
  int nchunks = n16 >> 4;
  int hc = nchunks >> 1;
  int jlo = (blockIdx.y == 0) ? 0 : hc * 16;
  int jhi = (blockIdx.y == 0) ? hc * 16 : n16;
  unsigned int r = 0;
  for (int j = jlo; j < jhi; j += 16) {
#pragma unroll
    for (int t = 0; t < 16; ++t) {
      r += (kb[j + t] < my) ? 1u : 0u;
    }
  }
  if (r) atomicAdd(&rank[(size_t)b * CAP + i], r);
}

// ---------------- 4b. scatter + box decode ----------------
__global__ __launch_bounds__(256) void scatter_kernel(const float4* __restrict__ anchors4,
                                                      const float4* __restrict__ bbox4,
                                                      const int* __restrict__ cnt,
                                                      const ull* __restrict__ keys,
                                                      const unsigned int* __restrict__ rank,
                                                      float4* __restrict__ boxes4) {
#pragma clang fp contract(off)
  int b = blockIdx.y;
  int n = cnt[b * 16];
  if (n > CAP) n = CAP;
  int i = blockIdx.x * 256 + threadIdx.x;
  if (i >= n) return;
  unsigned int r = rank[(size_t)b * CAP + i];
  if (r >= (unsigned)KSEL) return;
  int a = (int)(unsigned int)(keys[(size_t)b * CAP + i] & 0xffffffffull);
  float4 anc = anchors4[(size_t)b * NA + a];
  float4 d   = bbox4[(size_t)b * NA + a];
  float h = anc.z - anc.x;
  float w = anc.w - anc.y;
  float dy = d.x * 0.1f, dx = d.y * 0.1f, dh = d.z * 0.2f, dw = d.w * 0.2f;
  float cy = (anc.x + (0.5f * h)) + (dy * h);
  float cx = (anc.y + (0.5f * w)) + (dx * w);
  float h2 = h * expf(dh);
  float w2 = w * expf(dw);
  float y1 = cy - 0.5f * h2;
  float x1 = cx - 0.5f * w2;
  float y2 = y1 + h2;
  float x2 = x1 + w2;
  y1 = fminf(fmaxf(y1, 0.f), 1.f);
  x1 = fminf(fmaxf(x1, 0.f), 1.f);
  y2 = fminf(fmaxf(y2, 0.f), 1.f);
  x2 = fminf(fmaxf(x2, 0.f), 1.f);
  boxes4[(size_t)b * KSEL + r] = make_float4(y1, x1, y2, x2);
}

// ---------------- 5. suppression mask, ROW-major [b][row][96] words ----------------
__global__ __launch_bounds__(256) void mask_kernel(const float4* __restrict__ boxes4,
                                                   ull* __restrict__ mask) {
  int cx = blockIdx.x, rb = blockIdx.y, b = blockIdx.z;
  int cb0 = rb + 4 * cx;
  if (cb0 >= NWP) return;
  __shared__ float4 colbox[4][64];
  __shared__ ull wtile[64][5];
  int tid = threadIdx.x, wv = tid >> 6, l = tid & 63;
  int cb = cb0 + wv;
  int row = rb * 64 + l;
  float4 r = (row < KSEL) ? boxes4[(size_t)b * KSEL + row] : make_float4(0.f, 0.f, 0.f, 0.f);
  float ra = (r.z - r.x) * (r.w - r.y);
  int c = cb * 64 + l;
  colbox[wv][l] = (cb < NB && c < KSEL) ? boxes4[(size_t)b * KSEL + c]
                                        : make_float4(0.f, 0.f, 0.f, 0.f);
  __syncthreads();
  ull bits = 0ull;
  if (cb < NB) {
#pragma unroll
    for (int u = 0; u < 64; ++u) {
      float4 cbx = colbox[wv][u];
      float ca = (cbx.z - cbx.x) * (cbx.w - cbx.y);
      float ih = fmaxf(fminf(r.z, cbx.z) - fmaxf(r.x, cbx.x), 0.f);
      float iw = fmaxf(fminf(r.w, cbx.w) - fmaxf(r.y, cbx.y), 0.f);
      float inter = ih * iw;
      float uni = (ra + ca) - inter;
      float d = inter - 0.7f * uni;
      float tt = 6e-7f * uni;
      bool keep;
      if (__builtin_fabsf(d) <= tt) {
        keep = (inter / uni) > 0.7f;   // exact tie-region path (rare; NaN for 0/0 -> false)
      } else {
        keep = d > 0.f;
      }
      if (keep) bits |= (1ull << u);
    }
    if (cb == rb) {
      bits &= (l == 63) ? 0ull : (~0ull << (l + 1)); // only cc > row suppress
    }
  }
  wtile[l][wv] = bits;
  __syncthreads();
  int nrows = min(64, KSEL - rb * 64);
  int rr = tid >> 2, w = tid & 3;
  if (rr < nrows && cb0 + w < NWP)
    mask[((size_t)b * KSEL + (size_t)(rb * 64 + rr)) * NWP + cb0 + w] = wtile[rr][w];
}

// ---------------- 6. single-wave block-scalar greedy scan ----------------
__global__ __launch_bounds__(64, 1) void scan_kernel(const float4* __restrict__ boxes4,
                                                     const ull* __restrict__ mask,
                                                     float4* __restrict__ out4) {
  __shared__ int skeep[PROP];
  int b = blockIdx.x;
  int lane = threadIdx.x;
  const ull* mb = mask + (size_t)b * KSEL * NWP;
  int col = (2 * lane < NB) ? 2 * lane : NB;   // lanes >=47 -> pad words 94,95 (zeros)

  ull Sx = 0ull, Sy = 0ull;                    // suppressed words 2*lane, 2*lane+1
  int kept = 0;
  bool done = false;

  ull dg = mb[(size_t)lane * NWP + 0];         // block 0 diagonal word (row=lane)

  for (int n = 0; n < NBLK && !done; ++n) {
    int i0 = n * 64;
    asm volatile("" : : "v"(dg));

    // (a) issue all 64 row loads (addresses independent of decisions)
    ulonglong2 rr[64];
#pragma unroll
    for (int u = 0; u < 64; ++u) {
      int ur = i0 + u;
      ur = (ur < KSEL) ? ur : (KSEL - 1);
      rr[u] = *(const ulonglong2*)(mb + (size_t)ur * NWP + col);
    }
    // (b) next block's diagonal prefetch
    ull dgN = 0ull;
    if (n + 1 < NBLK) {
      int rn = (n + 1) * 64 + lane;
      if (rn >= KSEL) rn = KSEL - 1;
      dgN = mb[(size_t)rn * NWP + (n + 1)];
    }

    // (c) scalar greedy decision for this block
    int ol = n >> 1;
    ull Ssel = (n & 1) ? Sy : Sx;
    unsigned slo = (unsigned)__builtin_amdgcn_readlane((int)(unsigned)Ssel, ol);
    unsigned shi = (unsigned)__builtin_amdgcn_readlane((int)(unsigned)(Ssel >> 32), ol);
    ull Sw = (ull)slo | ((ull)shi << 32);
    int nval = KSEL - i0;
    ull valid = (nval >= 64) ? ~0ull : ((1ull << nval) - 1ull);
    ull A = ~Sw & valid;
    ull K = 0ull;
    unsigned vlo = (unsigned)dg, vhi = (unsigned)(dg >> 32);

    while (A) {
      int u = __builtin_ctzll(A);
      if (lane == 0) skeep[kept] = i0 + u;
      ++kept;
      K |= (1ull << u);
      if (kept >= PROP) { done = true; break; }
      ull Mu = (ull)(unsigned)__builtin_amdgcn_readlane((int)vlo, u)
             | ((ull)(unsigned)__builtin_amdgcn_readlane((int)vhi, u) << 32);
      A &= ~(Mu | (1ull << u));
    }

    // (d) OR kept rows into distributed S with uniform SGPR masks
    if (!done) {
#pragma unroll
      for (int u = 0; u < 64; ++u) {
        ull msk = 0ull - ((K >> u) & 1ull);    // wave-uniform: all-ones or 0
        Sx |= rr[u].x & msk;
        Sy |= rr[u].y & msk;
      }
    }
    dg = dgN;
  }

  __syncthreads();
  int fin = kept;
  for (int rr2 = lane; rr2 < PROP; rr2 += 64) {
    float4 v = make_float4(0.f, 0.f, 0.f, 0.f);
    if (rr2 < fin) v = boxes4[(size_t)b * KSEL + skeep[rr2]];
    out4[(size_t)b * PROP + rr2] = v;
  }
}

// ---------------- launch ----------------
extern "C" void kernel_launch(void* const* d_in, const int* in_sizes, int n_in,
                              void* d_out, int out_size, void* d_ws, size_t ws_size,
                              hipStream_t stream) {
  const float2* probs   = (const float2*)d_in[0];
  const float4* bbox4   = (const float4*)d_in[1];
  const float4* anchors4= (const float4*)d_in[2];
  float4* out4 = (float4*)d_out;
  char* ws = (char*)d_ws;

  int* cnt           = (int*)(ws + OFF_CNT);
  int* tsel          = (int*)(ws + OFF_TSEL);
  float4* boxes4     = (float4*)(ws + OFF_BOXES);
  ull* maskw         = (ull*)(ws + OFF_MASK);
  ull* keys          = (ull*)(ws + OFF_KEYS);
  unsigned int* rank = (unsigned int*)(ws + OFF_RANK);
  unsigned int* hist = (unsigned int*)(ws + OFF_HIST);

  hipMemsetAsync(ws + OFF_CNT, 0, 544, stream);
  hipMemsetAsync(ws + OFF_KEYS, 0xFF, 524288, stream);  // pad keys = +inf
  hipMemsetAsync(ws + OFF_RANK, 0, 262144, stream);

  hipLaunchKernelGGL(hist_kernel,    dim3(HB, BATCH),     dim3(256), 0, stream, probs, hist);
  hipLaunchKernelGGL(thresh_kernel,  dim3(BATCH),         dim3(256), 0, stream, hist, tsel);
  hipLaunchKernelGGL(compact_kernel, dim3(128, BATCH),    dim3(256), 0, stream, probs, tsel, cnt, keys);
  hipLaunchKernelGGL(rank_kernel,    dim3(32, 2, BATCH),  dim3(256), 0, stream, cnt, keys, rank);
  hipLaunchKernelGGL(scatter_kernel, dim3(32, BATCH),     dim3(256), 0, stream, anchors4, bbox4, cnt, keys, rank, boxes4);
  hipLaunchKernelGGL(mask_kernel,    dim3(24, NB, BATCH), dim3(256), 0, stream, boxes4, maskw);
  hipLaunchKernelGGL(scan_kernel,    dim3(BATCH),         dim3(64),  0, stream, boxes4, maskw, out4);
}